// Round 1
// baseline (2263.703 us; speedup 1.0000x reference)
//
#include <hip/hip_runtime.h>
#include <stdint.h>

typedef __attribute__((ext_vector_type(4))) float f32x4;
typedef __attribute__((ext_vector_type(8))) __bf16 bf16x8;

__device__ __forceinline__ ushort f2bf(float f) {
  union { float f; uint32_t u; } v; v.f = f;
  uint32_t r = v.u + 0x7fffu + ((v.u >> 16) & 1u);
  return (ushort)(r >> 16);
}
__device__ __forceinline__ float bf2f(uint32_t h) {
  union { uint32_t u; float f; } v; v.u = h << 16;
  return v.f;
}

// async global->LDS, 16 bytes per lane. LDS dest must be linear: lane i of the
// wave lands at (wave-uniform base) + i*16.
__device__ __forceinline__ void gload16(const void* g, const void* l) {
  __builtin_amdgcn_global_load_lds(
      (const __attribute__((address_space(1))) void*)(uintptr_t)g,
      (__attribute__((address_space(3))) void*)(uint32_t)(uintptr_t)l,
      16, 0, 0);
}

// ---------------------------------------------------------------------------
// GEMM: C(M,N) = A(M,K) * B^T(N,K)   (A row-major lda, Bt row-major ldb=K-ish)
// 128x128 tile, BK=32, 256 threads (4 waves, 2x2), mfma_f32_16x16x32_bf16.
// EPI 0: out bf16 = relu(acc + bias[n])
// EPI 1: out f32 z[r,n] (+)= gates[r*16+e] * (acc + bias[n])   (first -> store)
// EPI 2: out f32 = acc + bias[n]
// ---------------------------------------------------------------------------
template<int EPI>
__global__ __launch_bounds__(256)
void gemm_bt(const ushort* __restrict__ A, const ushort* __restrict__ Bt,
             const float* __restrict__ bias, void* __restrict__ outp,
             int M, int N, int K, int lda, int ldb, int ldo,
             const float* __restrict__ gates, int eidx, int first)
{
  __shared__ __attribute__((aligned(16))) ushort As[128 * 32];
  __shared__ __attribute__((aligned(16))) ushort Bs[128 * 32];

  const int t    = threadIdx.x;
  const int lane = t & 63;
  const int wid  = t >> 6;
  const int wr   = wid >> 1, wc = wid & 1;    // 2x2 wave grid, each wave 64x64
  const int fr   = lane & 15, fq = lane >> 4; // fragment row / k-quarter
  const int bx   = blockIdx.x, by = blockIdx.y;

  // staging: each thread stages 16B for A (rows 0-63), 16B (rows 64-127), same for B
  const int arow = t >> 2;
  const int acol = (t & 3) * 8;
  const ushort* Ag = A  + (size_t)(by * 128 + arow) * lda + acol;
  const ushort* Bg = Bt + (size_t)(bx * 128 + arow) * ldb + acol;

  f32x4 acc[4][4];
#pragma unroll
  for (int m = 0; m < 4; ++m)
#pragma unroll
    for (int n = 0; n < 4; ++n) acc[m][n] = (f32x4){0.f, 0.f, 0.f, 0.f};

  const ushort* aBase = &As[(wr * 64 + fr) * 32 + fq * 8];
  const ushort* bBase = &Bs[(wc * 64 + fr) * 32 + fq * 8];

  for (int k0 = 0; k0 < K; k0 += 32) {
    gload16(Ag,                     As + t * 8);
    gload16(Ag + (size_t)64 * lda,  As + t * 8 + 2048);
    gload16(Bg,                     Bs + t * 8);
    gload16(Bg + (size_t)64 * ldb,  Bs + t * 8 + 2048);
    __syncthreads();  // drains vmcnt(0): LDS tile complete

    bf16x8 af[4], bfr[4];
#pragma unroll
    for (int m = 0; m < 4; ++m) af[m]  = *(const bf16x8*)(aBase + m * 16 * 32);
#pragma unroll
    for (int n = 0; n < 4; ++n) bfr[n] = *(const bf16x8*)(bBase + n * 16 * 32);
#pragma unroll
    for (int m = 0; m < 4; ++m)
#pragma unroll
      for (int n = 0; n < 4; ++n)
        acc[m][n] = __builtin_amdgcn_mfma_f32_16x16x32_bf16(af[m], bfr[n], acc[m][n], 0, 0, 0);
    __syncthreads();  // protect LDS from next iteration's staging
    Ag += 32; Bg += 32;
  }

  // epilogue: D mapping col = lane&15, row = (lane>>4)*4 + j  [m89-verified]
  const int grow0 = by * 128 + wr * 64 + fq * 4;
  const int gcol0 = bx * 128 + wc * 64 + fr;
#pragma unroll
  for (int n = 0; n < 4; ++n) {
    const int c  = gcol0 + n * 16;
    const float bv = bias[c];
#pragma unroll
    for (int m = 0; m < 4; ++m) {
#pragma unroll
      for (int j = 0; j < 4; ++j) {
        const int r = grow0 + m * 16 + j;
        const float v = acc[m][n][j] + bv;
        if (EPI == 0) {
          ((ushort*)outp)[(size_t)r * ldo + c] = f2bf(v > 0.f ? v : 0.f);
        } else if (EPI == 1) {
          float* o = (float*)outp;
          const size_t idx = (size_t)r * ldo + c;
          float nv = gates[(size_t)r * 16 + eidx] * v;
          if (!first) nv += o[idx];
          o[idx] = nv;
        } else {
          ((float*)outp)[(size_t)r * ldo + c] = v;
        }
      }
    }
  }
}

// ---------------------------------------------------------------------------
// transpose + fp32->bf16 convert: in (K,N) f32  ->  out (N,K) bf16, batched z
// ---------------------------------------------------------------------------
__global__ __launch_bounds__(256)
void transpose_cvt(const float* __restrict__ in, ushort* __restrict__ out,
                   int K, int N, size_t inStride, size_t outStride)
{
  __shared__ float tile[32][33];
  const int z = blockIdx.z;
  const float* I = in + (size_t)z * inStride;
  ushort* O = out + (size_t)z * outStride;
  const int n0 = blockIdx.x * 32, k0 = blockIdx.y * 32;
  const int tx = threadIdx.x, ty = threadIdx.y; // (32,8)
#pragma unroll
  for (int i = 0; i < 32; i += 8) tile[ty + i][tx] = I[(size_t)(k0 + ty + i) * N + (n0 + tx)];
  __syncthreads();
#pragma unroll
  for (int i = 0; i < 32; i += 8) O[(size_t)(n0 + ty + i) * K + (k0 + tx)] = f2bf(tile[tx][ty + i]);
}

// x = concat(s, c) as bf16, row stride 1536. 8 elems/thread.
__global__ __launch_bounds__(256)
void build_x(const float* __restrict__ s, const float* __restrict__ c, ushort* __restrict__ x)
{
  const size_t i = (size_t)blockIdx.x * 256 + threadIdx.x; // 786432 total
  const size_t b = i / 192;
  const int col  = (int)(i % 192) * 8;
  const float* src = (col < 1024) ? (s + b * 1024 + col) : (c + b * 512 + (col - 1024));
  const float4 v0 = ((const float4*)src)[0];
  const float4 v1 = ((const float4*)src)[1];
  uint4 o;
  o.x = f2bf(v0.x) | ((uint32_t)f2bf(v0.y) << 16);
  o.y = f2bf(v0.z) | ((uint32_t)f2bf(v0.w) << 16);
  o.z = f2bf(v1.x) | ((uint32_t)f2bf(v1.y) << 16);
  o.w = f2bf(v1.z) | ((uint32_t)f2bf(v1.w) << 16);
  *(uint4*)(x + i * 8) = o;
}

__global__ __launch_bounds__(256)
void cvt_bf16(const float* __restrict__ in, ushort* __restrict__ out)
{
  const size_t i = (size_t)blockIdx.x * 256 + threadIdx.x;
  const float4 v0 = ((const float4*)(in + i * 8))[0];
  const float4 v1 = ((const float4*)(in + i * 8))[1];
  uint4 o;
  o.x = f2bf(v0.x) | ((uint32_t)f2bf(v0.y) << 16);
  o.y = f2bf(v0.z) | ((uint32_t)f2bf(v0.w) << 16);
  o.z = f2bf(v1.x) | ((uint32_t)f2bf(v1.y) << 16);
  o.w = f2bf(v1.z) | ((uint32_t)f2bf(v1.w) << 16);
  *(uint4*)(out + i * 8) = o;
}

// gating second layer + softmax: one wave per row.
// logits[e] = sum_k hg[row,k]*Wg2[k,e] + bg2[e];  gates = softmax(logits)
__global__ __launch_bounds__(256)
void gating2_softmax(const ushort* __restrict__ hg, const float* __restrict__ Wg2,
                     const float* __restrict__ bg2, float* __restrict__ gates)
{
  const int row  = (int)((blockIdx.x * 256 + threadIdx.x) >> 6);
  const int lane = threadIdx.x & 63;
  float acc[16];
#pragma unroll
  for (int e = 0; e < 16; ++e) acc[e] = 0.f;
  const ushort* hrow = hg + (size_t)row * 2048;
#pragma unroll
  for (int it = 0; it < 4; ++it) {
    const int kb = it * 512 + lane * 8;
    const uint4 pk = *(const uint4*)(hrow + kb);
    float hv[8] = { bf2f(pk.x & 0xffffu), bf2f(pk.x >> 16),
                    bf2f(pk.y & 0xffffu), bf2f(pk.y >> 16),
                    bf2f(pk.z & 0xffffu), bf2f(pk.z >> 16),
                    bf2f(pk.w & 0xffffu), bf2f(pk.w >> 16) };
#pragma unroll
    for (int j = 0; j < 8; ++j) {
      const float* wrow = Wg2 + (size_t)(kb + j) * 16;
#pragma unroll
      for (int e = 0; e < 16; ++e) acc[e] += hv[j] * wrow[e];
    }
  }
#pragma unroll
  for (int e = 0; e < 16; ++e) {
#pragma unroll
    for (int off = 32; off > 0; off >>= 1) acc[e] += __shfl_xor(acc[e], off);
    acc[e] += bg2[e];
  }
  float mx = acc[0];
#pragma unroll
  for (int e = 1; e < 16; ++e) mx = fmaxf(mx, acc[e]);
  float sum = 0.f;
#pragma unroll
  for (int e = 0; e < 16; ++e) { acc[e] = __expf(acc[e] - mx); sum += acc[e]; }
  const float inv = 1.f / sum;
  if (lane == 0) {
#pragma unroll
    for (int e = 0; e < 16; ++e) gates[(size_t)row * 16 + e] = acc[e] * inv;
  }
}

// ---------------------------------------------------------------------------
extern "C" void kernel_launch(void* const* d_in, const int* in_sizes, int n_in,
                              void* d_out, int out_size, void* d_ws, size_t ws_size,
                              hipStream_t stream)
{
  (void)in_sizes; (void)n_in; (void)out_size; (void)ws_size;
  const float* s   = (const float*)d_in[0];
  const float* c   = (const float*)d_in[1];
  const float* Wg1 = (const float*)d_in[2];
  const float* bg1 = (const float*)d_in[3];
  const float* Wg2 = (const float*)d_in[4];
  const float* bg2 = (const float*)d_in[5];
  const float* We1 = (const float*)d_in[6];
  const float* be1 = (const float*)d_in[7];
  const float* We2 = (const float*)d_in[8];
  const float* be2 = (const float*)d_in[9];
  const float* WA  = (const float*)d_in[10];
  const float* bA  = (const float*)d_in[11];
  const float* WB  = (const float*)d_in[12];
  const float* bB  = (const float*)d_in[13];
  float* out = (float*)d_out;

  char* ws = (char*)d_ws;
  size_t off = 0;
  auto alloc = [&](size_t bytes) {
    void* p = ws + off; off += (bytes + 255) & ~(size_t)255; return p;
  };
  ushort* x     = (ushort*)alloc((size_t)4096 * 1536 * 2);     // 12.6 MB
  ushort* Wg1T  = (ushort*)alloc((size_t)2048 * 1024 * 2);     //  4.2 MB
  ushort* We1T  = (ushort*)alloc((size_t)16 * 2048 * 1536 * 2);// 100.7 MB
  ushort* We2T  = (ushort*)alloc((size_t)16 * 512 * 2048 * 2); // 33.6 MB
  ushort* WAT   = (ushort*)alloc((size_t)16384 * 512 * 2);     // 16.8 MB
  ushort* WBT   = (ushort*)alloc((size_t)16384 * 512 * 2);     // 16.8 MB
  ushort* hg    = (ushort*)alloc((size_t)4096 * 2048 * 2);     // 16.8 MB
  ushort* h     = (ushort*)alloc((size_t)4096 * 2048 * 2);     // 16.8 MB
  float*  gates = (float*)alloc((size_t)4096 * 16 * 4);
  float*  z     = (float*)alloc((size_t)4096 * 512 * 4);       //  8.4 MB
  ushort* zb    = (ushort*)alloc((size_t)4096 * 512 * 2);      //  4.2 MB
  // total ~232 MB of d_ws

  const dim3 tb32(32, 8);
  build_x<<<3072, 256, 0, stream>>>(s, c, x);
  transpose_cvt<<<dim3(64, 32, 1),  tb32, 0, stream>>>(Wg1, Wg1T, 1024, 2048, 0, 0);
  transpose_cvt<<<dim3(64, 48, 16), tb32, 0, stream>>>(We1, We1T, 1536, 2048,
                                                       (size_t)1536 * 2048, (size_t)1536 * 2048);
  transpose_cvt<<<dim3(16, 64, 16), tb32, 0, stream>>>(We2, We2T, 2048, 512,
                                                       (size_t)2048 * 512, (size_t)2048 * 512);
  transpose_cvt<<<dim3(512, 16, 1), tb32, 0, stream>>>(WA, WAT, 512, 16384, 0, 0);
  transpose_cvt<<<dim3(512, 16, 1), tb32, 0, stream>>>(WB, WBT, 512, 16384, 0, 0);

  // gating: hg = relu(s @ Wg1 + bg1)   (uses first 1024 cols of x)
  gemm_bt<0><<<dim3(16, 32), 256, 0, stream>>>(x, Wg1T, bg1, hg,
                                               4096, 2048, 1024, 1536, 1024, 2048,
                                               nullptr, 0, 0);
  gating2_softmax<<<1024, 256, 0, stream>>>(hg, Wg2, bg2, gates);

  // experts, sequential, h buffer reused; z accumulated with gate weights
  for (int e = 0; e < 16; ++e) {
    gemm_bt<0><<<dim3(16, 32), 256, 0, stream>>>(x, We1T + (size_t)e * 2048 * 1536,
                                                 be1 + (size_t)e * 2048, h,
                                                 4096, 2048, 1536, 1536, 1536, 2048,
                                                 nullptr, 0, 0);
    gemm_bt<1><<<dim3(4, 32), 256, 0, stream>>>(h, We2T + (size_t)e * 512 * 2048,
                                                be2 + (size_t)e * 512, z,
                                                4096, 512, 2048, 2048, 2048, 512,
                                                gates, e, e == 0 ? 1 : 0);
  }
  cvt_bf16<<<1024, 256, 0, stream>>>(z, zb); // 4096*512/8 = 262144 threads

  // LoRA heads -> d_out (fp32): A then Bm, each (4096, 16384)
  gemm_bt<2><<<dim3(128, 32), 256, 0, stream>>>(zb, WAT, bA, out,
                                                4096, 16384, 512, 512, 512, 16384,
                                                nullptr, 0, 0);
  gemm_bt<2><<<dim3(128, 32), 256, 0, stream>>>(zb, WBT, bB, out + (size_t)4096 * 16384,
                                                4096, 16384, 512, 512, 512, 16384,
                                                nullptr, 0, 0);
}

// Round 2
// 1482.339 us; speedup vs baseline: 1.5271x; 1.5271x over previous
//
#include <hip/hip_runtime.h>
#include <stdint.h>

typedef __attribute__((ext_vector_type(4))) float f32x4;
typedef __attribute__((ext_vector_type(8))) __bf16 bf16x8;

__device__ __forceinline__ ushort f2bf(float f) {
  union { float f; uint32_t u; } v; v.f = f;
  uint32_t r = v.u + 0x7fffu + ((v.u >> 16) & 1u);
  return (ushort)(r >> 16);
}
__device__ __forceinline__ float bf2f(uint32_t h) {
  union { uint32_t u; float f; } v; v.u = h << 16;
  return v.f;
}

// async global->LDS, 16 bytes per lane; LDS dest is wave-uniform base + lane*16.
__device__ __forceinline__ void gload16(const void* g, const void* l) {
  __builtin_amdgcn_global_load_lds(
      (const __attribute__((address_space(1))) void*)(uintptr_t)g,
      (__attribute__((address_space(3))) void*)(uint32_t)(uintptr_t)l,
      16, 0, 0);
}

// ---------------------------------------------------------------------------
// GEMM: C(M,N) = A(M,K) * B^T(N,K), batched over blockIdx.z via strides.
// 128x128 tile, BK=32, 256 threads (4 waves 2x2), mfma_f32_16x16x32_bf16.
// EPI 0: out bf16 = relu(acc + bias[n])           (out += oStride*bz)
// EPI 1: atomicAdd(out[r,n], gates[r,ebase+bz] * (acc + bias[n]))
// EPI 3: fused LoRA: col < ldo -> out[r*ldo+c]+bias, else out+oStride, bias2
// ---------------------------------------------------------------------------
template<int EPI>
__global__ __launch_bounds__(256)
void gemm_bt(const ushort* __restrict__ A, const ushort* __restrict__ Bt,
             const float* __restrict__ bias, const float* __restrict__ bias2,
             void* __restrict__ outp,
             int M, int N, int K, int lda, int ldb, int ldo,
             size_t aStride, size_t bStride, int biasStride, size_t oStride,
             const float* __restrict__ gates, int ebase)
{
  (void)M; (void)N;
  __shared__ __attribute__((aligned(16))) ushort As[128 * 32];
  __shared__ __attribute__((aligned(16))) ushort Bs[128 * 32];

  const int t    = threadIdx.x;
  const int lane = t & 63;
  const int wid  = t >> 6;
  const int wr   = wid >> 1, wc = wid & 1;    // 2x2 wave grid, each wave 64x64
  const int fr   = lane & 15, fq = lane >> 4; // fragment row / k-quarter
  const int bx   = blockIdx.x, by = blockIdx.y, bz = blockIdx.z;

  const ushort* Ab  = A  + aStride * bz;
  const ushort* Btb = Bt + bStride * bz;
  const float*  bb  = bias + (size_t)biasStride * bz;

  const int arow = t >> 2;
  const int acol = (t & 3) * 8;
  const ushort* Ag = Ab  + (size_t)(by * 128 + arow) * lda + acol;
  const ushort* Bg = Btb + (size_t)(bx * 128 + arow) * ldb + acol;

  f32x4 acc[4][4];
#pragma unroll
  for (int m = 0; m < 4; ++m)
#pragma unroll
    for (int n = 0; n < 4; ++n) acc[m][n] = (f32x4){0.f, 0.f, 0.f, 0.f};

  const ushort* aBase = &As[(wr * 64 + fr) * 32 + fq * 8];
  const ushort* bBase = &Bs[(wc * 64 + fr) * 32 + fq * 8];

  for (int k0 = 0; k0 < K; k0 += 32) {
    gload16(Ag,                     As + t * 8);
    gload16(Ag + (size_t)64 * lda,  As + t * 8 + 2048);
    gload16(Bg,                     Bs + t * 8);
    gload16(Bg + (size_t)64 * ldb,  Bs + t * 8 + 2048);
    __syncthreads();

    bf16x8 af[4], bfr[4];
#pragma unroll
    for (int m = 0; m < 4; ++m) af[m]  = *(const bf16x8*)(aBase + m * 16 * 32);
#pragma unroll
    for (int n = 0; n < 4; ++n) bfr[n] = *(const bf16x8*)(bBase + n * 16 * 32);
#pragma unroll
    for (int m = 0; m < 4; ++m)
#pragma unroll
      for (int n = 0; n < 4; ++n)
        acc[m][n] = __builtin_amdgcn_mfma_f32_16x16x32_bf16(af[m], bfr[n], acc[m][n], 0, 0, 0);
    __syncthreads();
    Ag += 32; Bg += 32;
  }

  // D mapping: col = lane&15 (+n*16), row = (lane>>4)*4 + j (+m*16)  [m89]
  const int grow0 = by * 128 + wr * 64 + fq * 4;
  const int gcol0 = bx * 128 + wc * 64 + fr;

  if (EPI == 0) {
    ushort* o = (ushort*)outp + oStride * bz;
#pragma unroll
    for (int n = 0; n < 4; ++n) {
      const int c = gcol0 + n * 16;
      const float bv = bb[c];
#pragma unroll
      for (int m = 0; m < 4; ++m)
#pragma unroll
        for (int j = 0; j < 4; ++j) {
          const int r = grow0 + m * 16 + j;
          const float v = acc[m][n][j] + bv;
          o[(size_t)r * ldo + c] = f2bf(v > 0.f ? v : 0.f);
        }
    }
  } else if (EPI == 1) {
    float* o = (float*)outp;
    const int e = ebase + bz;
#pragma unroll
    for (int n = 0; n < 4; ++n) {
      const int c = gcol0 + n * 16;
      const float bv = bb[c];
#pragma unroll
      for (int m = 0; m < 4; ++m)
#pragma unroll
        for (int j = 0; j < 4; ++j) {
          const int r = grow0 + m * 16 + j;
          const float v = acc[m][n][j] + bv;
          atomicAdd(&o[(size_t)r * ldo + c], gates[(size_t)r * 16 + e] * v);
        }
    }
  } else { // EPI 3: fused LoRA heads
    const bool second = (gcol0 >= ldo);
    const float* bp = second ? bias2 : bias;
    float* o = (float*)outp + (second ? oStride : 0);
#pragma unroll
    for (int n = 0; n < 4; ++n) {
      const int cc = gcol0 + n * 16 - (second ? ldo : 0);
      const float bv = bp[cc];
#pragma unroll
      for (int m = 0; m < 4; ++m)
#pragma unroll
        for (int j = 0; j < 4; ++j) {
          const int r = grow0 + m * 16 + j;
          o[(size_t)r * ldo + cc] = acc[m][n][j] + bv;
        }
    }
  }
}

// ---------------------------------------------------------------------------
// transpose + cvt: in (K,N) f32 -> out (N,K) bf16. 64x64 tiles, vectorized.
// ---------------------------------------------------------------------------
__global__ __launch_bounds__(256)
void transpose_cvt(const float* __restrict__ in, ushort* __restrict__ out,
                   int K, int N, size_t inStride, size_t outStride)
{
  __shared__ float tile[64][65];
  const float* I = in + inStride * blockIdx.z;
  ushort* O = out + outStride * blockIdx.z;
  const int n0 = blockIdx.x * 64, k0 = blockIdx.y * 64;
  const int t = threadIdx.x;
  const int r = t >> 4, cv = (t & 15) * 4;
#pragma unroll
  for (int p = 0; p < 4; ++p) {
    const int kr = r + p * 16;
    const float4 v = *(const float4*)&I[(size_t)(k0 + kr) * N + (n0 + cv)];
    tile[kr][cv] = v.x; tile[kr][cv + 1] = v.y; tile[kr][cv + 2] = v.z; tile[kr][cv + 3] = v.w;
  }
  __syncthreads();
#pragma unroll
  for (int p = 0; p < 4; ++p) {
    const int nr = r + p * 16;
    ushort4 o4;
    o4.x = f2bf(tile[cv + 0][nr]); o4.y = f2bf(tile[cv + 1][nr]);
    o4.z = f2bf(tile[cv + 2][nr]); o4.w = f2bf(tile[cv + 3][nr]);
    *(ushort4*)&O[(size_t)(n0 + nr) * K + (k0 + cv)] = o4;
  }
}

// x = concat(s, c) as bf16, row stride 1536. 8 elems/thread.
__global__ __launch_bounds__(256)
void build_x(const float* __restrict__ s, const float* __restrict__ c, ushort* __restrict__ x)
{
  const size_t i = (size_t)blockIdx.x * 256 + threadIdx.x;
  const size_t b = i / 192;
  const int col  = (int)(i % 192) * 8;
  const float* src = (col < 1024) ? (s + b * 1024 + col) : (c + b * 512 + (col - 1024));
  const float4 v0 = ((const float4*)src)[0];
  const float4 v1 = ((const float4*)src)[1];
  uint4 o;
  o.x = f2bf(v0.x) | ((uint32_t)f2bf(v0.y) << 16);
  o.y = f2bf(v0.z) | ((uint32_t)f2bf(v0.w) << 16);
  o.z = f2bf(v1.x) | ((uint32_t)f2bf(v1.y) << 16);
  o.w = f2bf(v1.z) | ((uint32_t)f2bf(v1.w) << 16);
  *(uint4*)(x + i * 8) = o;
}

__global__ __launch_bounds__(256)
void cvt_bf16(const float* __restrict__ in, ushort* __restrict__ out)
{
  const size_t i = (size_t)blockIdx.x * 256 + threadIdx.x;
  const float4 v0 = ((const float4*)(in + i * 8))[0];
  const float4 v1 = ((const float4*)(in + i * 8))[1];
  uint4 o;
  o.x = f2bf(v0.x) | ((uint32_t)f2bf(v0.y) << 16);
  o.y = f2bf(v0.z) | ((uint32_t)f2bf(v0.w) << 16);
  o.z = f2bf(v1.x) | ((uint32_t)f2bf(v1.y) << 16);
  o.w = f2bf(v1.z) | ((uint32_t)f2bf(v1.w) << 16);
  *(uint4*)(out + i * 8) = o;
}

// gating second layer + softmax: one wave per row.
__global__ __launch_bounds__(256)
void gating2_softmax(const ushort* __restrict__ hg, const float* __restrict__ Wg2,
                     const float* __restrict__ bg2, float* __restrict__ gates)
{
  const int row  = (int)((blockIdx.x * 256 + threadIdx.x) >> 6);
  const int lane = threadIdx.x & 63;
  float acc[16];
#pragma unroll
  for (int e = 0; e < 16; ++e) acc[e] = 0.f;
  const ushort* hrow = hg + (size_t)row * 2048;
#pragma unroll
  for (int it = 0; it < 4; ++it) {
    const int kb = it * 512 + lane * 8;
    const uint4 pk = *(const uint4*)(hrow + kb);
    float hv[8] = { bf2f(pk.x & 0xffffu), bf2f(pk.x >> 16),
                    bf2f(pk.y & 0xffffu), bf2f(pk.y >> 16),
                    bf2f(pk.z & 0xffffu), bf2f(pk.z >> 16),
                    bf2f(pk.w & 0xffffu), bf2f(pk.w >> 16) };
#pragma unroll
    for (int j = 0; j < 8; ++j) {
      const float* wrow = Wg2 + (size_t)(kb + j) * 16;
#pragma unroll
      for (int e = 0; e < 16; ++e) acc[e] += hv[j] * wrow[e];
    }
  }
#pragma unroll
  for (int e = 0; e < 16; ++e) {
#pragma unroll
    for (int off = 32; off > 0; off >>= 1) acc[e] += __shfl_xor(acc[e], off);
    acc[e] += bg2[e];
  }
  float mx = acc[0];
#pragma unroll
  for (int e = 1; e < 16; ++e) mx = fmaxf(mx, acc[e]);
  float sum = 0.f;
#pragma unroll
  for (int e = 0; e < 16; ++e) { acc[e] = __expf(acc[e] - mx); sum += acc[e]; }
  const float inv = 1.f / sum;
  if (lane == 0) {
#pragma unroll
    for (int e = 0; e < 16; ++e) gates[(size_t)row * 16 + e] = acc[e] * inv;
  }
}

// ---------------------------------------------------------------------------
extern "C" void kernel_launch(void* const* d_in, const int* in_sizes, int n_in,
                              void* d_out, int out_size, void* d_ws, size_t ws_size,
                              hipStream_t stream)
{
  (void)in_sizes; (void)n_in; (void)out_size;
  const float* s   = (const float*)d_in[0];
  const float* c   = (const float*)d_in[1];
  const float* Wg1 = (const float*)d_in[2];
  const float* bg1 = (const float*)d_in[3];
  const float* Wg2 = (const float*)d_in[4];
  const float* bg2 = (const float*)d_in[5];
  const float* We1 = (const float*)d_in[6];
  const float* be1 = (const float*)d_in[7];
  const float* We2 = (const float*)d_in[8];
  const float* be2 = (const float*)d_in[9];
  const float* WA  = (const float*)d_in[10];
  const float* bA  = (const float*)d_in[11];
  const float* WB  = (const float*)d_in[12];
  const float* bB  = (const float*)d_in[13];
  float* out = (float*)d_out;

  char* ws = (char*)d_ws;
  size_t off = 0;
  auto alloc = [&](size_t bytes) {
    void* p = ws + off; off += (bytes + 255) & ~(size_t)255; return p;
  };
  ushort* x     = (ushort*)alloc((size_t)4096 * 1536 * 2);      // 12.6 MB
  ushort* We1T  = (ushort*)alloc((size_t)16 * 2048 * 1536 * 2); // 100.7 MB
  ushort* We2T  = (ushort*)alloc((size_t)16 * 512 * 2048 * 2);  // 33.6 MB
  ushort* WABT  = (ushort*)alloc((size_t)32768 * 512 * 2);      // 33.6 MB
  float*  gates = (float*)alloc((size_t)4096 * 16 * 4);
  float*  z     = (float*)alloc((size_t)4096 * 512 * 4);        //  8.4 MB
  ushort* zb    = (ushort*)alloc((size_t)4096 * 512 * 2);       //  4.2 MB

  // expert group size, limited by remaining workspace for h
  const size_t BH = (size_t)4096 * 2048 * 2; // 16.8 MB per expert
  size_t rem = (ws_size > off) ? ws_size - off : 0;
  int GS = 2;
  if (rem >= 8 * BH) GS = 8;
  else if (rem >= 4 * BH) GS = 4;
  ushort* h = (ushort*)alloc((size_t)GS * BH);
  // aliases inside h (dead before h is first written):
  ushort* Wg1T = h;                                        // 4.2 MB
  ushort* hg   = (ushort*)((char*)h + (size_t)2048 * 1024 * 2); // 16.8 MB

  const size_t S_We1 = (size_t)2048 * 1536; // Bt stride per expert (elems)
  const size_t S_We2 = (size_t)512 * 2048;
  const size_t S_h   = (size_t)4096 * 2048;

  build_x<<<3072, 256, 0, stream>>>(s, c, x);
  transpose_cvt<<<dim3(32, 16, 1),  256, 0, stream>>>(Wg1, Wg1T, 1024, 2048, 0, 0);
  transpose_cvt<<<dim3(32, 24, 16), 256, 0, stream>>>(We1, We1T, 1536, 2048, S_We1, S_We1);
  transpose_cvt<<<dim3(8, 32, 16),  256, 0, stream>>>(We2, We2T, 2048, 512, S_We2, S_We2);
  transpose_cvt<<<dim3(256, 8, 1),  256, 0, stream>>>(WA, WABT, 512, 16384, 0, 0);
  transpose_cvt<<<dim3(256, 8, 1),  256, 0, stream>>>(WB, WABT + (size_t)16384 * 512, 512, 16384, 0, 0);

  // gating: hg = relu(s @ Wg1 + bg1), then gates = softmax(hg @ Wg2 + bg2)
  gemm_bt<0><<<dim3(16, 32, 1), 256, 0, stream>>>(x, Wg1T, bg1, nullptr, hg,
      4096, 2048, 1024, 1536, 1024, 2048, 0, 0, 0, 0, nullptr, 0);
  gating2_softmax<<<1024, 256, 0, stream>>>(hg, Wg2, bg2, gates);

  hipMemsetAsync(z, 0, (size_t)4096 * 512 * 4, stream);

  for (int g = 0; g < 16; g += GS) {
    // h[e] = relu(x @ We1[e]^T + be1[e]) for e in [g, g+GS)
    gemm_bt<0><<<dim3(16, 32, GS), 256, 0, stream>>>(x, We1T + (size_t)g * S_We1,
        be1 + (size_t)g * 2048, nullptr, h,
        4096, 2048, 1536, 1536, 1536, 2048, 0, S_We1, 2048, S_h, nullptr, 0);
    // z += gates[:,e] * (h[e] @ We2[e]^T + be2[e])   (atomic split-K over experts)
    gemm_bt<1><<<dim3(4, 32, GS), 256, 0, stream>>>(h, We2T + (size_t)g * S_We2,
        be2 + (size_t)g * 512, nullptr, z,
        4096, 512, 2048, 2048, 2048, 512, S_h, S_We2, 512, 0, gates, g);
  }

  cvt_bf16<<<1024, 256, 0, stream>>>(z, zb);

  // fused LoRA heads: C = zb @ [WA; WB]^T, split-output epilogue
  gemm_bt<3><<<dim3(256, 32, 1), 256, 0, stream>>>(zb, WABT, bA, bB, out,
      4096, 32768, 512, 512, 512, 16384, 0, 0, 0, (size_t)4096 * 16384, nullptr, 0);
}